// Round 6
// baseline (111.261 us; speedup 1.0000x reference)
//
#include <hip/hip_runtime.h>
#include <math.h>

// Problem constants
#define BATCH 4
#define NNODE 10000
#define EDIM  32
#define CDIM  128
#define ODIM  128
#define MTOT  (BATCH * NNODE)   // 40000

typedef __attribute__((ext_vector_type(8))) short bf16x8;   // MFMA A/B frag (4 VGPRs)
typedef __attribute__((ext_vector_type(4))) float f32x4;    // MFMA C/D frag

__device__ __forceinline__ unsigned short f2bf(float f) {
    unsigned u = __float_as_uint(f);
    u += 0x7fffu + ((u >> 16) & 1u);   // RTNE
    return (unsigned short)(u >> 16);
}
__device__ __forceinline__ float bf2f(unsigned short h) {
    return __uint_as_float(((unsigned)h) << 16);
}

// ---------------------------------------------------------------------------
// prep_w: Bcat[n][k] bf16, n-major so GEMM B-fragments are contiguous 16B
// loads. n<128: W1[k][n]-W2[k][n]; n>=128: W2[k][n-128]. 64KB, L2-hot.
// Also fills sentinel T row (row 40000) with -inf bf16 (branch-free gather).
// ---------------------------------------------------------------------------
__global__ __launch_bounds__(256) void prep_w(
    const float* __restrict__ W, unsigned short* __restrict__ Bcat,
    unsigned short* __restrict__ Tsent)
{
    int gid = blockIdx.x * 256 + threadIdx.x;   // 32768 threads
    int n = gid >> 7;          // 0..255
    int k = gid & 127;         // 0..127
    float v;
    if (n < 128) v = W[(size_t)k * ODIM + n] - W[(size_t)(k + 128) * ODIM + n];
    else         v = W[(size_t)(k + 128) * ODIM + (n - 128)];
    Bcat[(size_t)n * CDIM + k] = f2bf(v);
    if (gid < ODIM) Tsent[gid] = 0xFF80;        // -inf bf16
}

// ---------------------------------------------------------------------------
// MFMA GEMM, LDS-staged. BM=32: block = 32 rows x 256 cols (cols 0..127 -> U
// bf16+bias, 128..255 -> T bf16). 1250 blocks -> ~4.9/CU (2% tail vs 23% at
// BM=64). 4 waves x 64-col quarter, 2x4 tiles of 16x16x32, K=128.
// A: coalesced float4 x-loads, fp32->bf16 in staging, kblk-XOR-swizzled LDS
// (writes+ds_read_b128 both <=2-way = free). B: direct 16B loads from L2-hot
// Bcat (each instr = 16 full 64B lines).
// Epilogue: acc -> LDS (pitch 132 floats, quad rows land 16 banks apart) ->
// coalesced ushort4 stores for BOTH U and T (was 64 scalar stores/thread).
// Layouts (R4/R5-verified): A[m=lane&15][k=quad*8+j], B[k=quad*8+j][n=lane&15],
// C/D col=lane&15, row=quad*4+reg.
// ---------------------------------------------------------------------------
__global__ __launch_bounds__(256) void gemm_mfma(
    const float* __restrict__ x,            // [40000,128]
    const unsigned short* __restrict__ Bcat,// [256,128] bf16
    const float* __restrict__ bias,         // [128]
    unsigned short* __restrict__ U,         // [40000,128] bf16
    unsigned short* __restrict__ T)         // [40001,128] bf16
{
    __shared__ char lds_raw[32 * 132 * 4];  // 16.9 KB: staging (8KB) then epilogue
    unsigned short* As = (unsigned short*)lds_raw;   // [32][128] swizzled
    float*          Cf = (float*)lds_raw;            // [32][132]

    const int tid  = threadIdx.x;
    const int m0   = blockIdx.x * 32;
    const int wv   = tid >> 6;
    const int lane = tid & 63;
    const int l16  = lane & 15;
    const int quad = lane >> 4;
    const int nq   = wv * 64;

    // ---- stage + convert: 32 rows x 128 k, coalesced float4 reads ----
    #pragma unroll
    for (int i = 0; i < 4; i++) {
        int lin = i * 256 + tid;            // float4 index, 0..1023
        int row = lin >> 5;                 // 0..31
        int f4  = lin & 31;                 // float4 within row
        float4 v = *(const float4*)&x[(size_t)(m0 + row) * CDIM + f4 * 4];
        ushort4 h;
        h.x = f2bf(v.x); h.y = f2bf(v.y); h.z = f2bf(v.z); h.w = f2bf(v.w);
        int kblk = f4 >> 1, half = f4 & 1;
        *(ushort4*)((char*)As + row * 256 + (((kblk ^ (row & 15)) << 4) + half * 8)) = h;
    }
    __syncthreads();

    f32x4 acc[2][4];
    #pragma unroll
    for (int i = 0; i < 2; i++)
        #pragma unroll
        for (int j = 0; j < 4; j++) acc[i][j] = (f32x4){0.f, 0.f, 0.f, 0.f};

    #pragma unroll
    for (int ks = 0; ks < 4; ks++) {
        const int kb = ks * 32 + quad * 8;

        bf16x8 bfr[4];
        #pragma unroll
        for (int ct = 0; ct < 4; ct++)
            bfr[ct] = *(const bf16x8*)(Bcat + (size_t)(nq + ct * 16 + l16) * CDIM + kb);

        bf16x8 afr[2];
        #pragma unroll
        for (int rt = 0; rt < 2; rt++) {
            int row  = rt * 16 + l16;
            int kblk = ks * 4 + quad;
            afr[rt] = *(const bf16x8*)((char*)As + row * 256 + ((kblk ^ l16) << 4));
        }

        #pragma unroll
        for (int rt = 0; rt < 2; rt++)
            #pragma unroll
            for (int ct = 0; ct < 4; ct++)
                acc[rt][ct] = __builtin_amdgcn_mfma_f32_16x16x32_bf16(
                    afr[rt], bfr[ct], acc[rt][ct], 0, 0, 0);
    }

    // ---- epilogue: LDS transpose -> coalesced ushort4 stores ----
    __syncthreads();                        // As reads done, reuse LDS
    if (wv < 2) {                           // U cols 0..127
        #pragma unroll
        for (int rt = 0; rt < 2; rt++)
            #pragma unroll
            for (int ct = 0; ct < 4; ct++)
                #pragma unroll
                for (int r = 0; r < 4; r++)
                    Cf[(rt * 16 + quad * 4 + r) * 132 + nq + ct * 16 + l16] = acc[rt][ct][r];
    }
    __syncthreads();
    #pragma unroll
    for (int i = 0; i < 4; i++) {           // 32 rows x 128 cols
        int lin = i * 256 + tid;
        int row = lin >> 5, f4 = lin & 31;
        float4 v  = *(const float4*)&Cf[row * 132 + f4 * 4];
        float4 bb = *(const float4*)&bias[f4 * 4];
        ushort4 h;
        h.x = f2bf(v.x + bb.x); h.y = f2bf(v.y + bb.y);
        h.z = f2bf(v.z + bb.z); h.w = f2bf(v.w + bb.w);
        *(ushort4*)&U[(size_t)(m0 + row) * ODIM + f4 * 4] = h;
    }
    __syncthreads();
    if (wv >= 2) {                          // T cols 0..127
        #pragma unroll
        for (int rt = 0; rt < 2; rt++)
            #pragma unroll
            for (int ct = 0; ct < 4; ct++)
                #pragma unroll
                for (int r = 0; r < 4; r++)
                    Cf[(rt * 16 + quad * 4 + r) * 132 + (nq - 128) + ct * 16 + l16] = acc[rt][ct][r];
    }
    __syncthreads();
    #pragma unroll
    for (int i = 0; i < 4; i++) {
        int lin = i * 256 + tid;
        int row = lin >> 5, f4 = lin & 31;
        float4 v = *(const float4*)&Cf[row * 132 + f4 * 4];
        ushort4 h;
        h.x = f2bf(v.x); h.y = f2bf(v.y); h.z = f2bf(v.z); h.w = f2bf(v.w);
        *(ushort4*)&T[(size_t)(m0 + row) * ODIM + f4 * 4] = h;
    }
}

// ---------------------------------------------------------------------------
// Gather + max + elu. Quarter-wave (16 lanes) per node, uint4 = bf16x8 per
// lane -> one 1KB load instr per edge row. Invalid indices rewritten at
// staging to the -inf sentinel row -> pure branch-free gather-max; "any
// valid" = m[0] > -inf. 16 loads in flight (x2). U read is one uint4 (bf16).
// XCD swizzle b=g&3: each XCD touches one batch's 2.56MB T slice (< 4MB L2).
// ---------------------------------------------------------------------------
__global__ __launch_bounds__(256) void gather_max(
    const int* __restrict__ idx,            // [40000,32]
    const unsigned short* __restrict__ Ub,  // [40000,128] bf16 (ws)
    const unsigned short* __restrict__ T,   // [40001,128] bf16 (ws)
    float* __restrict__ out)                // [40000,128] (d_out)
{
    __shared__ int sidx[16][EDIM];

    const int g   = blockIdx.x;             // 0..2499
    const int b   = g & 3;                  // batch
    const int nb0 = (g >> 2) * 16;          // first node (0..9984)
    const int tid = threadIdx.x;
    const int sent = NNODE * (BATCH - b);   // sentinel row rel. to tb

    #pragma unroll
    for (int i = 0; i < 2; i++) {
        int lin = i * 256 + tid;            // 0..511
        int n = lin >> 5, e = lin & 31;
        int j = idx[(size_t)(b * NNODE + nb0 + n) * EDIM + e];
        sidx[n][e] = (j < 0) ? sent : j;
    }
    __syncthreads();

    const int wv   = tid >> 6;
    const int lane = tid & 63;
    const int q4   = lane >> 4;
    const int l16  = lane & 15;
    const int myn  = wv * 4 + q4;           // 0..15
    const int node = b * NNODE + nb0 + myn;
    const unsigned short* tb = T + (size_t)b * NNODE * ODIM;
    const int o8 = l16 * 8;                 // bf16 col offset (16B aligned)

    uint4 uraw = *(const uint4*)(Ub + (size_t)node * ODIM + o8);  // prefetch U

    float m[8];
    #pragma unroll
    for (int i = 0; i < 8; i++) m[i] = -INFINITY;

    #pragma unroll
    for (int e0 = 0; e0 < EDIM; e0 += 16) {
        uint4 v[16];
        #pragma unroll
        for (int q = 0; q < 16; q++) {      // 16 gathers in flight
            int j = sidx[myn][e0 + q];
            v[q] = *(const uint4*)(tb + (size_t)j * ODIM + o8);
        }
        #pragma unroll
        for (int q = 0; q < 16; q++) {
            m[0] = fmaxf(m[0], __uint_as_float(v[q].x << 16));
            m[1] = fmaxf(m[1], __uint_as_float(v[q].x & 0xffff0000u));
            m[2] = fmaxf(m[2], __uint_as_float(v[q].y << 16));
            m[3] = fmaxf(m[3], __uint_as_float(v[q].y & 0xffff0000u));
            m[4] = fmaxf(m[4], __uint_as_float(v[q].z << 16));
            m[5] = fmaxf(m[5], __uint_as_float(v[q].z & 0xffff0000u));
            m[6] = fmaxf(m[6], __uint_as_float(v[q].w << 16));
            m[7] = fmaxf(m[7], __uint_as_float(v[q].w & 0xffff0000u));
        }
    }

    const bool any = m[0] > -INFINITY;      // all-invalid => every m[i] = -inf
    float uu[8];
    uu[0] = bf2f((unsigned short)(uraw.x & 0xffff)); uu[1] = bf2f((unsigned short)(uraw.x >> 16));
    uu[2] = bf2f((unsigned short)(uraw.y & 0xffff)); uu[3] = bf2f((unsigned short)(uraw.y >> 16));
    uu[4] = bf2f((unsigned short)(uraw.z & 0xffff)); uu[5] = bf2f((unsigned short)(uraw.z >> 16));
    uu[6] = bf2f((unsigned short)(uraw.w & 0xffff)); uu[7] = bf2f((unsigned short)(uraw.w >> 16));
    float r[8];
    #pragma unroll
    for (int i = 0; i < 8; i++) {
        float s = uu[i] + m[i];
        r[i] = any ? (s > 0.f ? s : __expf(s) - 1.f) : -INFINITY;
    }
    *(float4*)&out[(size_t)node * ODIM + o8]     = make_float4(r[0], r[1], r[2], r[3]);
    *(float4*)&out[(size_t)node * ODIM + o8 + 4] = make_float4(r[4], r[5], r[6], r[7]);
}

extern "C" void kernel_launch(void* const* d_in, const int* in_sizes, int n_in,
                              void* d_out, int out_size, void* d_ws, size_t ws_size,
                              hipStream_t stream) {
    const float* x    = (const float*)d_in[0];
    const int*   idx  = (const int*)d_in[1];
    const float* W    = (const float*)d_in[2];
    const float* bias = (const float*)d_in[3];
    float* out        = (float*)d_out;

    // ws layout: T bf16 [(40000+1)*128] | U bf16 [40000*128] | Bcat bf16 [256*128]
    const size_t tBytes = (size_t)(MTOT + 1) * ODIM * sizeof(unsigned short);
    const size_t uBytes = (size_t)MTOT * ODIM * sizeof(unsigned short);
    unsigned short* T    = (unsigned short*)d_ws;
    unsigned short* U    = (unsigned short*)((char*)d_ws + tBytes);
    unsigned short* Bcat = (unsigned short*)((char*)d_ws + tBytes + uBytes);
    unsigned short* Tsent = T + (size_t)MTOT * ODIM;

    prep_w    <<<128,        256, 0, stream>>>(W, Bcat, Tsent);
    gemm_mfma <<<MTOT / 32,  256, 0, stream>>>(x, Bcat, bias, U, T);
    gather_max<<<MTOT / 16,  256, 0, stream>>>(idx, U, T, out);
}